// Round 5
// baseline (324.103 us; speedup 1.0000x reference)
//
#include <hip/hip_runtime.h>
#include <hip/hip_bf16.h>
#include <math.h>

#define BN 8
#define DEMB 128
#define NP 3072
#define MSPLIT 8
#define MRANGE (NP / MSPLIT)   // 384 m per block
#define NCHUNK (MRANGE / 64)   // 6 chunks of 64 m
#define NBLK 128               // n per block
#define NWAVE 32               // n per wave

#define QT_ELEMS ((size_t)BN * NP * DEMB)

typedef __attribute__((ext_vector_type(8))) short short8;
typedef __attribute__((ext_vector_type(4))) float f32x4;

__device__ inline float fast_exp2(float x) {
#if __has_builtin(__builtin_amdgcn_exp2f)
    return __builtin_amdgcn_exp2f(x);
#else
    return __expf(x * 0.6931471805599453f);
#endif
}

__device__ inline void load_lds16(const ushort* g, ushort* l) {
    __builtin_amdgcn_global_load_lds(
        (const __attribute__((address_space(1))) unsigned int*)g,
        (__attribute__((address_space(3))) unsigned int*)l,
        16, 0, 0);
}

// ------------------------------------------------------------------
// k_prep: fp32 [b][d][n] -> bf16 [b][n][d], LDS-staged coalesced writes
// ------------------------------------------------------------------
#define PSTRIDE 132

__global__ __launch_bounds__(256) void k_prep(const float* __restrict__ qe,
                                              const float* __restrict__ te,
                                              ushort* __restrict__ qT,
                                              ushort* __restrict__ eT)
{
    __shared__ ushort lds[4][16 * PSTRIDE];

    const int bid = blockIdx.x;            // 2 * 8 * 48 = 768
    const int t   = bid & 1;
    const int b   = (bid >> 1) & 7;
    const int nb  = bid >> 4;              // 0..47

    const float* src = (t ? te : qe) + (size_t)b * DEMB * NP;
    ushort*      dst = (t ? eT : qT) + (size_t)b * NP * DEMB;

    const int w    = threadIdx.x >> 6;
    const int lane = threadIdx.x & 63;
    const int n0   = nb * 64 + w * 16;

#pragma unroll
    for (int p = 0; p < 8; ++p) {
        const int d  = p * 16 + (lane >> 2);
        const int nn = (lane & 3) * 4;
        const f32x4 v = *(const f32x4*)(src + (size_t)d * NP + n0 + nn);
#pragma unroll
        for (int k = 0; k < 4; ++k) {
            __hip_bfloat16 h = __float2bfloat16(v[k]);
            lds[w][(nn + k) * PSTRIDE + d] = *reinterpret_cast<ushort*>(&h);
        }
    }
    __syncthreads();

#pragma unroll
    for (int q = 0; q < 8; ++q) {
        const int flat = q * 256 + lane * 4;
        const int n = flat >> 7;
        const int d = flat & 127;
        uint2 vv;
        vv.x = *(const uint*)&lds[w][n * PSTRIDE + d];
        vv.y = *(const uint*)&lds[w][n * PSTRIDE + d + 2];
        *(uint2*)(dst + ((size_t)(n0 + n)) * DEMB + d) = vv;
    }
}

// ------------------------------------------------------------------
// k_attn: LDS double-buffered MFMA scores + raw-exp softmax accumulation.
// e-chunk (64m x 128 bf16 = 16KB) staged via global_load_lds; the LDS
// layout applies chunk-swizzle sc = c ^ (row&7) realized by PRE-SWIZZLING
// the per-lane global source address (linear LDS dest, rule #21), and the
// ds_read_b128 side applies the same XOR. Counted vmcnt(4) keeps the
// next-chunk DMA in flight across raw s_barriers. tgt slice in LDS.
// ------------------------------------------------------------------
__global__ __launch_bounds__(256, 4) void k_attn(const ushort* __restrict__ qT,
                                                 const ushort* __restrict__ eT,
                                                 const float* __restrict__ tgt,
                                                 float4* __restrict__ part)
{
    __shared__ ushort ebuf[2][64 * 128];   // 2 x 16KB
    __shared__ float  tbuf[3][MRANGE];     // tgt slice for this ms (4.6KB)

    const int bid  = blockIdx.x;           // 1536 = 8b * 24nblk * 8ms
    const int b    = bid & 7;              // batch -> XCD pinning
    const int r    = bid >> 3;
    const int nblk = r % 24;
    const int ms   = r / 24;

    const int wid  = threadIdx.x >> 6;
    const int lane = threadIdx.x & 63;
    const int g    = lane >> 4;
    const int c16  = lane & 15;

    const int nw = nblk * NBLK + wid * NWAVE;
    const ushort* qb = qT + (size_t)b * NP * DEMB;
    const ushort* eb = eT + (size_t)b * NP * DEMB;
    const float*  tp = tgt + (size_t)b * 3 * NP;
    const int m_base = ms * MRANGE;

    // staging offsets: LDS slot s = wid*256 + i*64 + lane holds row (s>>4),
    // swizzled chunk (s&15); its global source is chunk c = (s&15) ^ (row&7).
    int goff[4], loff[4];
#pragma unroll
    for (int i = 0; i < 4; ++i) {
        const int row = wid * 16 + i * 4 + g;
        const int ch  = c16 ^ (row & 7);
        goff[i] = row * DEMB + ch * 8;
        loff[i] = (wid * 256 + i * 64) * 8;   // wave-uniform ushort offset
    }

    // B-frags (q), resident for the whole m-loop
    short8 bq[2][4];
#pragma unroll
    for (int ns = 0; ns < 2; ++ns)
#pragma unroll
        for (int kf = 0; kf < 4; ++kf)
            bq[ns][kf] = *(const short8*)(qb + (size_t)(nw + ns * 16 + c16) * DEMB
                                          + kf * 32 + g * 8);

    // stage chunk 0 into buffer 0
    {
        const ushort* gsrc = eb + (size_t)m_base * DEMB;
#pragma unroll
        for (int i = 0; i < 4; ++i)
            load_lds16(gsrc + goff[i], &ebuf[0][0] + loff[i]);
    }

    // stage tgt slice into LDS
    for (int j = threadIdx.x; j < 3 * MRANGE; j += 256) {
        const int c = j / MRANGE, jm = j % MRANGE;
        tbuf[c][jm] = tp[c * NP + m_base + jm];
    }

    float o[2][4];
#pragma unroll
    for (int ns = 0; ns < 2; ++ns)
        o[ns][0] = o[ns][1] = o[ns][2] = o[ns][3] = 0.f;

    const float scale2 = 0.12752962736873462f;  // log2(e)/sqrt(128)

    __syncthreads();   // drains chunk-0 DMA + tbuf writes (vmcnt/lgkm 0)

#pragma unroll
    for (int mc = 0; mc < NCHUNK; ++mc) {
        const int cur = mc & 1;

        // issue prefetch of chunk mc+1 into the other buffer
        if (mc + 1 < NCHUNK) {
            const ushort* gsrc = eb + (size_t)(m_base + (mc + 1) * 64) * DEMB;
            ushort* ldst = &ebuf[cur ^ 1][0];
#pragma unroll
            for (int i = 0; i < 4; ++i)
                load_lds16(gsrc + goff[i], ldst + loff[i]);
        }

        // wait for chunk mc's 4 loads (leave the 4 just issued in flight)
        if (mc + 1 < NCHUNK)
            asm volatile("s_waitcnt vmcnt(4)" ::: "memory");
        else
            asm volatile("s_waitcnt vmcnt(0)" ::: "memory");
        __builtin_amdgcn_s_barrier();
        __builtin_amdgcn_sched_barrier(0);

        // ---- compute on ebuf[cur] (no VMEM in this phase) ----
        const ushort* ebase = &ebuf[cur][0];
        f32x4 s[4][2];
#pragma unroll
        for (int msub = 0; msub < 4; ++msub) {
            const int rowoff = (msub * 16 + c16) * 128;
            const int x7 = c16 & 7;
            const short8 a0 = *(const short8*)(ebase + rowoff + ((0 * 4 + g) ^ x7) * 8);
            const short8 a1 = *(const short8*)(ebase + rowoff + ((1 * 4 + g) ^ x7) * 8);
            const short8 a2 = *(const short8*)(ebase + rowoff + ((2 * 4 + g) ^ x7) * 8);
            const short8 a3 = *(const short8*)(ebase + rowoff + ((3 * 4 + g) ^ x7) * 8);
            f32x4 c0 = {0.f, 0.f, 0.f, 0.f};
            f32x4 c1 = {0.f, 0.f, 0.f, 0.f};
            c0 = __builtin_amdgcn_mfma_f32_16x16x32_bf16(a0, bq[0][0], c0, 0, 0, 0);
            c0 = __builtin_amdgcn_mfma_f32_16x16x32_bf16(a1, bq[0][1], c0, 0, 0, 0);
            c0 = __builtin_amdgcn_mfma_f32_16x16x32_bf16(a2, bq[0][2], c0, 0, 0, 0);
            c0 = __builtin_amdgcn_mfma_f32_16x16x32_bf16(a3, bq[0][3], c0, 0, 0, 0);
            c1 = __builtin_amdgcn_mfma_f32_16x16x32_bf16(a0, bq[1][0], c1, 0, 0, 0);
            c1 = __builtin_amdgcn_mfma_f32_16x16x32_bf16(a1, bq[1][1], c1, 0, 0, 0);
            c1 = __builtin_amdgcn_mfma_f32_16x16x32_bf16(a2, bq[1][2], c1, 0, 0, 0);
            c1 = __builtin_amdgcn_mfma_f32_16x16x32_bf16(a3, bq[1][3], c1, 0, 0, 0);
            s[msub][0] = c0;
            s[msub][1] = c1;
        }

#pragma unroll
        for (int msub = 0; msub < 4; ++msub) {
            const int lm = mc * 64 + msub * 16 + g * 4;
            const f32x4 t0 = *(const f32x4*)&tbuf[0][lm];
            const f32x4 t1 = *(const f32x4*)&tbuf[1][lm];
            const f32x4 t2 = *(const f32x4*)&tbuf[2][lm];
#pragma unroll
            for (int rr = 0; rr < 4; ++rr) {
#pragma unroll
                for (int ns = 0; ns < 2; ++ns) {
                    const float p = fast_exp2(s[msub][ns][rr] * scale2);
                    o[ns][3] += p;
                    o[ns][0] = fmaf(p, t0[rr], o[ns][0]);
                    o[ns][1] = fmaf(p, t1[rr], o[ns][1]);
                    o[ns][2] = fmaf(p, t2[rr], o[ns][2]);
                }
            }
        }

        // all waves done reading ebuf[cur] before next iter's DMA targets it
        if (mc + 1 < NCHUNK) {
            asm volatile("" ::: "memory");
            __builtin_amdgcn_s_barrier();
            asm volatile("" ::: "memory");
        }
    }

    // reduce over the 4 m-row lane groups, write float4 partial
#pragma unroll
    for (int ns = 0; ns < 2; ++ns) {
#pragma unroll
        for (int v = 0; v < 4; ++v) {
            o[ns][v] += __shfl_xor(o[ns][v], 16);
            o[ns][v] += __shfl_xor(o[ns][v], 32);
        }
        if (g == 0) {
            const int n = nw + ns * 16 + c16;
            float4 pv;
            pv.x = o[ns][0]; pv.y = o[ns][1]; pv.z = o[ns][2]; pv.w = o[ns][3];
            part[((size_t)ms * BN + b) * NP + n] = pv;
        }
    }
}

// ------------------------------------------------------------------
// k_final: fused combine + per-batch reduction + 3x3 SVD + R, t, euler
// ------------------------------------------------------------------
__global__ __launch_bounds__(256) void k_final(const float* __restrict__ src,
                                               const float4* __restrict__ part,
                                               float* __restrict__ out)
{
    const int b = blockIdx.x;
    const float* sp = src + (size_t)b * 3 * NP;

    double acc[15];
#pragma unroll
    for (int v = 0; v < 15; ++v) acc[v] = 0.0;

    for (int n = threadIdx.x; n < NP; n += 256) {
        float o0 = 0.f, o1 = 0.f, o2 = 0.f, l = 0.f;
#pragma unroll
        for (int s = 0; s < MSPLIT; ++s) {
            const float4 pp = part[((size_t)s * BN + b) * NP + n];
            o0 += pp.x; o1 += pp.y; o2 += pp.z; l += pp.w;
        }
        const double inv = 1.0 / (double)l;
        const double y0 = o0 * inv, y1 = o1 * inv, y2 = o2 * inv;
        const double x0 = sp[n], x1 = sp[NP + n], x2 = sp[2 * NP + n];
        acc[0] += x0; acc[1] += x1; acc[2] += x2;
        acc[3] += y0; acc[4] += y1; acc[5] += y2;
        acc[6]  += x0 * y0; acc[7]  += x0 * y1; acc[8]  += x0 * y2;
        acc[9]  += x1 * y0; acc[10] += x1 * y1; acc[11] += x1 * y2;
        acc[12] += x2 * y0; acc[13] += x2 * y1; acc[14] += x2 * y2;
    }

    const int wid = threadIdx.x >> 6, lane = threadIdx.x & 63;
#pragma unroll
    for (int v = 0; v < 15; ++v)
#pragma unroll
        for (int mask = 32; mask >= 1; mask >>= 1)
            acc[v] += __shfl_xor(acc[v], mask);

    __shared__ double red[4][15];
    if (lane == 0) {
#pragma unroll
        for (int v = 0; v < 15; ++v) red[wid][v] = acc[v];
    }
    __syncthreads();
    if (threadIdx.x != 0) return;

    double t15[15];
#pragma unroll
    for (int v = 0; v < 15; ++v)
        t15[v] = red[0][v] + red[1][v] + red[2][v] + red[3][v];

    const double invN = 1.0 / NP;
    const double mx[3] = {t15[0] * invN, t15[1] * invN, t15[2] * invN};
    const double my[3] = {t15[3] * invN, t15[4] * invN, t15[5] * invN};
    double H[3][3];
#pragma unroll
    for (int i = 0; i < 3; ++i)
#pragma unroll
        for (int j = 0; j < 3; ++j)
            H[i][j] = t15[6 + i * 3 + j] - (double)NP * mx[i] * my[j];

    double A[3][3], V[3][3];
#pragma unroll
    for (int i = 0; i < 3; ++i)
#pragma unroll
        for (int j = 0; j < 3; ++j) {
            A[i][j] = H[0][i] * H[0][j] + H[1][i] * H[1][j] + H[2][i] * H[2][j];
            V[i][j] = (i == j) ? 1.0 : 0.0;
        }

    for (int sweep = 0; sweep < 12; ++sweep) {
        const int pqs[3][2] = {{0, 1}, {0, 2}, {1, 2}};
        for (int k = 0; k < 3; ++k) {
            const int p = pqs[k][0], q = pqs[k][1];
            const double apq = A[p][q];
            if (apq * apq <= 1e-24 * (A[p][p] * A[p][p] + A[q][q] * A[q][q]))
                continue;
            const double theta = (A[q][q] - A[p][p]) / (2.0 * apq);
            const double tj = (theta >= 0 ? 1.0 : -1.0) /
                              (fabs(theta) + sqrt(theta * theta + 1.0));
            const double c = 1.0 / sqrt(tj * tj + 1.0);
            const double s = tj * c;
            for (int i = 0; i < 3; ++i) {
                const double aip = A[i][p], aiq = A[i][q];
                A[i][p] = c * aip - s * aiq;
                A[i][q] = s * aip + c * aiq;
            }
            for (int i = 0; i < 3; ++i) {
                const double api = A[p][i], aqi = A[q][i];
                A[p][i] = c * api - s * aqi;
                A[q][i] = s * api + c * aqi;
            }
            for (int i = 0; i < 3; ++i) {
                const double vip = V[i][p], viq = V[i][q];
                V[i][p] = c * vip - s * viq;
                V[i][q] = s * vip + c * viq;
            }
        }
    }

    double lam[3] = {A[0][0], A[1][1], A[2][2]};
    int ord[3] = {0, 1, 2};
    for (int i = 0; i < 2; ++i)
        for (int j = i + 1; j < 3; ++j)
            if (lam[ord[j]] > lam[ord[i]]) { int t = ord[i]; ord[i] = ord[j]; ord[j] = t; }

    double Vs[3][3], sv[3];
    for (int j = 0; j < 3; ++j) {
        sv[j] = sqrt(fmax(lam[ord[j]], 0.0));
        for (int i = 0; i < 3; ++i) Vs[i][j] = V[i][ord[j]];
    }
    double U[3][3];
    for (int j = 0; j < 3; ++j) {
        const double h0 = H[0][0] * Vs[0][j] + H[0][1] * Vs[1][j] + H[0][2] * Vs[2][j];
        const double h1 = H[1][0] * Vs[0][j] + H[1][1] * Vs[1][j] + H[1][2] * Vs[2][j];
        const double h2 = H[2][0] * Vs[0][j] + H[2][1] * Vs[1][j] + H[2][2] * Vs[2][j];
        const double inv = 1.0 / fmax(sv[j], 1e-300);
        U[0][j] = h0 * inv; U[1][j] = h1 * inv; U[2][j] = h2 * inv;
    }

    double R[3][3];
    for (int i = 0; i < 3; ++i)
        for (int j = 0; j < 3; ++j)
            R[i][j] = Vs[i][0] * U[j][0] + Vs[i][1] * U[j][1] + Vs[i][2] * U[j][2];
    const double det =
        R[0][0] * (R[1][1] * R[2][2] - R[1][2] * R[2][1]) -
        R[0][1] * (R[1][0] * R[2][2] - R[1][2] * R[2][0]) +
        R[0][2] * (R[1][0] * R[2][1] - R[1][1] * R[2][0]);
    if (det < 0.0) {
        Vs[0][2] = -Vs[0][2]; Vs[1][2] = -Vs[1][2]; Vs[2][2] = -Vs[2][2];
        for (int i = 0; i < 3; ++i)
            for (int j = 0; j < 3; ++j)
                R[i][j] = Vs[i][0] * U[j][0] + Vs[i][1] * U[j][1] + Vs[i][2] * U[j][2];
    }

    double tvec[3];
    for (int i = 0; i < 3; ++i)
        tvec[i] = -(R[i][0] * mx[0] + R[i][1] * mx[1] + R[i][2] * mx[2]) + my[i];

    const double ex = atan2(R[2][1], R[2][2]);
    const double syv = sqrt(R[0][0] * R[0][0] + R[1][0] * R[1][0]);
    const double ey = atan2(-R[2][0], syv);
    const double ez = atan2(R[1][0], R[0][0]);

    for (int i = 0; i < 3; ++i)
        for (int j = 0; j < 3; ++j)
            out[b * 9 + i * 3 + j] = (float)R[i][j];
    out[72 + b * 3 + 0] = (float)tvec[0];
    out[72 + b * 3 + 1] = (float)tvec[1];
    out[72 + b * 3 + 2] = (float)tvec[2];
    out[96 + b * 3 + 0] = (float)ex;
    out[96 + b * 3 + 1] = (float)ey;
    out[96 + b * 3 + 2] = (float)ez;
}

// ------------------------------------------------------------------
extern "C" void kernel_launch(void* const* d_in, const int* in_sizes, int n_in,
                              void* d_out, int out_size, void* d_ws, size_t ws_size,
                              hipStream_t stream) {
    const float* qe  = (const float*)d_in[0];  // src_embedding [B,128,N]
    const float* te  = (const float*)d_in[1];  // tgt_embedding [B,128,N]
    const float* src = (const float*)d_in[2];  // src [B,3,N]
    const float* tgt = (const float*)d_in[3];  // tgt [B,3,N]
    float* out = (float*)d_out;

    ushort* qT   = (ushort*)d_ws;                    // bf16 [b][n][d] 6.3MB
    ushort* eT   = qT + QT_ELEMS;                    // bf16 [b][m][d] 6.3MB
    float4* part = (float4*)(eT + QT_ELEMS);         // MSPLIT*BN*NP float4

    k_prep<<<768, 256, 0, stream>>>(qe, te, qT, eT);
    k_attn<<<1536, 256, 0, stream>>>(qT, eT, tgt, part);
    k_final<<<BN, 256, 0, stream>>>(src, part, out);
}

// Round 6
// 104.633 us; speedup vs baseline: 3.0975x; 3.0975x over previous
//
#include <hip/hip_runtime.h>
#include <hip/hip_bf16.h>
#include <math.h>

#define BN 8
#define DEMB 128
#define NP 3072
#define MSPLIT 8
#define MRANGE (NP / MSPLIT)   // 384 m per block
#define NBLK 128               // n per block
#define NWAVE 32               // n per wave

#define QT_ELEMS ((size_t)BN * NP * DEMB)

typedef __attribute__((ext_vector_type(8))) short short8;
typedef __attribute__((ext_vector_type(4))) float f32x4;

__device__ inline float fast_exp2(float x) {
#if __has_builtin(__builtin_amdgcn_exp2f)
    return __builtin_amdgcn_exp2f(x);
#else
    return __expf(x * 0.6931471805599453f);
#endif
}

// ------------------------------------------------------------------
// k_prep: fp32 [b][d][n] -> bf16 [b][n][d], LDS-staged coalesced writes
// ------------------------------------------------------------------
#define PSTRIDE 132

__global__ __launch_bounds__(256) void k_prep(const float* __restrict__ qe,
                                              const float* __restrict__ te,
                                              ushort* __restrict__ qT,
                                              ushort* __restrict__ eT)
{
    __shared__ ushort lds[4][16 * PSTRIDE];

    const int bid = blockIdx.x;            // 2 * 8 * 48 = 768
    const int t   = bid & 1;
    const int b   = (bid >> 1) & 7;
    const int nb  = bid >> 4;              // 0..47

    const float* src = (t ? te : qe) + (size_t)b * DEMB * NP;
    ushort*      dst = (t ? eT : qT) + (size_t)b * NP * DEMB;

    const int w    = threadIdx.x >> 6;
    const int lane = threadIdx.x & 63;
    const int n0   = nb * 64 + w * 16;

#pragma unroll
    for (int p = 0; p < 8; ++p) {
        const int d  = p * 16 + (lane >> 2);
        const int nn = (lane & 3) * 4;
        const f32x4 v = *(const f32x4*)(src + (size_t)d * NP + n0 + nn);
#pragma unroll
        for (int k = 0; k < 4; ++k) {
            __hip_bfloat16 h = __float2bfloat16(v[k]);
            lds[w][(nn + k) * PSTRIDE + d] = *reinterpret_cast<ushort*>(&h);
        }
    }
    __syncthreads();

#pragma unroll
    for (int q = 0; q < 8; ++q) {
        const int flat = q * 256 + lane * 4;
        const int n = flat >> 7;
        const int d = flat & 127;
        uint2 vv;
        vv.x = *(const uint*)&lds[w][n * PSTRIDE + d];
        vv.y = *(const uint*)&lds[w][n * PSTRIDE + d + 2];
        *(uint2*)(dst + ((size_t)(n0 + n)) * DEMB + d) = vv;
    }
}

// ------------------------------------------------------------------
// k_attn: direct-global-load MFMA scores (S^T: rows=m, cols=n) + raw-exp
// softmax accumulation, restructured as fine-grained 16-row steps so
// consecutive steps' A-loads overlap the previous step's exp/PV chain.
// tgt slice staged once in LDS (broadcast ds_reads). No in-loop barriers.
// ------------------------------------------------------------------
__global__ __launch_bounds__(256) void k_attn(const ushort* __restrict__ qT,
                                              const ushort* __restrict__ eT,
                                              const float* __restrict__ tgt,
                                              float4* __restrict__ part)
{
    __shared__ float tbuf[3][MRANGE];      // 4.6 KB tgt slice

    const int bid  = blockIdx.x;           // 1536 = 8b * 24nblk * 8ms
    const int b    = bid & 7;              // batch -> XCD pinning
    const int r    = bid >> 3;
    const int nblk = r % 24;
    const int ms   = r / 24;

    const int wid  = threadIdx.x >> 6;
    const int lane = threadIdx.x & 63;
    const int g    = lane >> 4;
    const int c16  = lane & 15;

    const int nw = nblk * NBLK + wid * NWAVE;
    const ushort* qb = qT + (size_t)b * NP * DEMB;
    const ushort* eb = eT + (size_t)b * NP * DEMB;
    const float*  tp = tgt + (size_t)b * 3 * NP;
    const int m_base = ms * MRANGE;

    // stage tgt slice into LDS (one time)
    for (int j = threadIdx.x; j < 3 * MRANGE; j += 256) {
        const int c = j / MRANGE, jm = j % MRANGE;
        tbuf[c][jm] = tp[c * NP + m_base + jm];
    }

    // B-frags (q), resident for the whole m-loop
    short8 bq[2][4];
#pragma unroll
    for (int ns = 0; ns < 2; ++ns)
#pragma unroll
        for (int kf = 0; kf < 4; ++kf)
            bq[ns][kf] = *(const short8*)(qb + (size_t)(nw + ns * 16 + c16) * DEMB
                                          + kf * 32 + g * 8);

    float o[2][4];   // o0,o1,o2,l
#pragma unroll
    for (int ns = 0; ns < 2; ++ns)
        o[ns][0] = o[ns][1] = o[ns][2] = o[ns][3] = 0.f;

    const float scale2 = 0.12752962736873462f;  // log2(e)/sqrt(128)

    __syncthreads();   // tbuf visible to all waves

    // 24 fine-grained steps of 16 m-rows each
#pragma unroll 2
    for (int st = 0; st < MRANGE / 16; ++st) {
        const int mloc = st * 16;
        const ushort* ar = eb + (size_t)(m_base + mloc + c16) * DEMB + g * 8;
        const short8 a0 = *(const short8*)(ar);
        const short8 a1 = *(const short8*)(ar + 32);
        const short8 a2 = *(const short8*)(ar + 64);
        const short8 a3 = *(const short8*)(ar + 96);

        f32x4 c0 = {0.f, 0.f, 0.f, 0.f};
        f32x4 c1 = {0.f, 0.f, 0.f, 0.f};
        c0 = __builtin_amdgcn_mfma_f32_16x16x32_bf16(a0, bq[0][0], c0, 0, 0, 0);
        c0 = __builtin_amdgcn_mfma_f32_16x16x32_bf16(a1, bq[0][1], c0, 0, 0, 0);
        c0 = __builtin_amdgcn_mfma_f32_16x16x32_bf16(a2, bq[0][2], c0, 0, 0, 0);
        c0 = __builtin_amdgcn_mfma_f32_16x16x32_bf16(a3, bq[0][3], c0, 0, 0, 0);
        c1 = __builtin_amdgcn_mfma_f32_16x16x32_bf16(a0, bq[1][0], c1, 0, 0, 0);
        c1 = __builtin_amdgcn_mfma_f32_16x16x32_bf16(a1, bq[1][1], c1, 0, 0, 0);
        c1 = __builtin_amdgcn_mfma_f32_16x16x32_bf16(a2, bq[1][2], c1, 0, 0, 0);
        c1 = __builtin_amdgcn_mfma_f32_16x16x32_bf16(a3, bq[1][3], c1, 0, 0, 0);

        // tgt values for this step's 4 m-rows (broadcast ds_read, 16B)
        const f32x4 t0 = *(const f32x4*)&tbuf[0][mloc + g * 4];
        const f32x4 t1 = *(const f32x4*)&tbuf[1][mloc + g * 4];
        const f32x4 t2 = *(const f32x4*)&tbuf[2][mloc + g * 4];

#pragma unroll
        for (int rr = 0; rr < 4; ++rr) {
            const float p0 = fast_exp2(c0[rr] * scale2);
            o[0][3] += p0;
            o[0][0] = fmaf(p0, t0[rr], o[0][0]);
            o[0][1] = fmaf(p0, t1[rr], o[0][1]);
            o[0][2] = fmaf(p0, t2[rr], o[0][2]);
            const float p1 = fast_exp2(c1[rr] * scale2);
            o[1][3] += p1;
            o[1][0] = fmaf(p1, t0[rr], o[1][0]);
            o[1][1] = fmaf(p1, t1[rr], o[1][1]);
            o[1][2] = fmaf(p1, t2[rr], o[1][2]);
        }
    }

    // reduce over the 4 m-row lane groups, write float4 partial
#pragma unroll
    for (int ns = 0; ns < 2; ++ns) {
#pragma unroll
        for (int v = 0; v < 4; ++v) {
            o[ns][v] += __shfl_xor(o[ns][v], 16);
            o[ns][v] += __shfl_xor(o[ns][v], 32);
        }
        if (g == 0) {
            const int n = nw + ns * 16 + c16;
            float4 pv;
            pv.x = o[ns][0]; pv.y = o[ns][1]; pv.z = o[ns][2]; pv.w = o[ns][3];
            part[((size_t)ms * BN + b) * NP + n] = pv;
        }
    }
}

// ------------------------------------------------------------------
// k_final: fused combine + per-batch reduction + 3x3 SVD + R, t, euler
// ------------------------------------------------------------------
__global__ __launch_bounds__(256) void k_final(const float* __restrict__ src,
                                               const float4* __restrict__ part,
                                               float* __restrict__ out)
{
    const int b = blockIdx.x;
    const float* sp = src + (size_t)b * 3 * NP;

    double acc[15];
#pragma unroll
    for (int v = 0; v < 15; ++v) acc[v] = 0.0;

    for (int n = threadIdx.x; n < NP; n += 256) {
        float o0 = 0.f, o1 = 0.f, o2 = 0.f, l = 0.f;
#pragma unroll
        for (int s = 0; s < MSPLIT; ++s) {
            const float4 pp = part[((size_t)s * BN + b) * NP + n];
            o0 += pp.x; o1 += pp.y; o2 += pp.z; l += pp.w;
        }
        const double inv = 1.0 / (double)l;
        const double y0 = o0 * inv, y1 = o1 * inv, y2 = o2 * inv;
        const double x0 = sp[n], x1 = sp[NP + n], x2 = sp[2 * NP + n];
        acc[0] += x0; acc[1] += x1; acc[2] += x2;
        acc[3] += y0; acc[4] += y1; acc[5] += y2;
        acc[6]  += x0 * y0; acc[7]  += x0 * y1; acc[8]  += x0 * y2;
        acc[9]  += x1 * y0; acc[10] += x1 * y1; acc[11] += x1 * y2;
        acc[12] += x2 * y0; acc[13] += x2 * y1; acc[14] += x2 * y2;
    }

    const int wid = threadIdx.x >> 6, lane = threadIdx.x & 63;
#pragma unroll
    for (int v = 0; v < 15; ++v)
#pragma unroll
        for (int mask = 32; mask >= 1; mask >>= 1)
            acc[v] += __shfl_xor(acc[v], mask);

    __shared__ double red[4][15];
    if (lane == 0) {
#pragma unroll
        for (int v = 0; v < 15; ++v) red[wid][v] = acc[v];
    }
    __syncthreads();
    if (threadIdx.x != 0) return;

    double t15[15];
#pragma unroll
    for (int v = 0; v < 15; ++v)
        t15[v] = red[0][v] + red[1][v] + red[2][v] + red[3][v];

    const double invN = 1.0 / NP;
    const double mx[3] = {t15[0] * invN, t15[1] * invN, t15[2] * invN};
    const double my[3] = {t15[3] * invN, t15[4] * invN, t15[5] * invN};
    double H[3][3];
#pragma unroll
    for (int i = 0; i < 3; ++i)
#pragma unroll
        for (int j = 0; j < 3; ++j)
            H[i][j] = t15[6 + i * 3 + j] - (double)NP * mx[i] * my[j];

    double A[3][3], V[3][3];
#pragma unroll
    for (int i = 0; i < 3; ++i)
#pragma unroll
        for (int j = 0; j < 3; ++j) {
            A[i][j] = H[0][i] * H[0][j] + H[1][i] * H[1][j] + H[2][i] * H[2][j];
            V[i][j] = (i == j) ? 1.0 : 0.0;
        }

    for (int sweep = 0; sweep < 12; ++sweep) {
        const int pqs[3][2] = {{0, 1}, {0, 2}, {1, 2}};
        for (int k = 0; k < 3; ++k) {
            const int p = pqs[k][0], q = pqs[k][1];
            const double apq = A[p][q];
            if (apq * apq <= 1e-24 * (A[p][p] * A[p][p] + A[q][q] * A[q][q]))
                continue;
            const double theta = (A[q][q] - A[p][p]) / (2.0 * apq);
            const double tj = (theta >= 0 ? 1.0 : -1.0) /
                              (fabs(theta) + sqrt(theta * theta + 1.0));
            const double c = 1.0 / sqrt(tj * tj + 1.0);
            const double s = tj * c;
            for (int i = 0; i < 3; ++i) {
                const double aip = A[i][p], aiq = A[i][q];
                A[i][p] = c * aip - s * aiq;
                A[i][q] = s * aip + c * aiq;
            }
            for (int i = 0; i < 3; ++i) {
                const double api = A[p][i], aqi = A[q][i];
                A[p][i] = c * api - s * aqi;
                A[q][i] = s * api + c * aqi;
            }
            for (int i = 0; i < 3; ++i) {
                const double vip = V[i][p], viq = V[i][q];
                V[i][p] = c * vip - s * viq;
                V[i][q] = s * vip + c * viq;
            }
        }
    }

    double lam[3] = {A[0][0], A[1][1], A[2][2]};
    int ord[3] = {0, 1, 2};
    for (int i = 0; i < 2; ++i)
        for (int j = i + 1; j < 3; ++j)
            if (lam[ord[j]] > lam[ord[i]]) { int t = ord[i]; ord[i] = ord[j]; ord[j] = t; }

    double Vs[3][3], sv[3];
    for (int j = 0; j < 3; ++j) {
        sv[j] = sqrt(fmax(lam[ord[j]], 0.0));
        for (int i = 0; i < 3; ++i) Vs[i][j] = V[i][ord[j]];
    }
    double U[3][3];
    for (int j = 0; j < 3; ++j) {
        const double h0 = H[0][0] * Vs[0][j] + H[0][1] * Vs[1][j] + H[0][2] * Vs[2][j];
        const double h1 = H[1][0] * Vs[0][j] + H[1][1] * Vs[1][j] + H[1][2] * Vs[2][j];
        const double h2 = H[2][0] * Vs[0][j] + H[2][1] * Vs[1][j] + H[2][2] * Vs[2][j];
        const double inv = 1.0 / fmax(sv[j], 1e-300);
        U[0][j] = h0 * inv; U[1][j] = h1 * inv; U[2][j] = h2 * inv;
    }

    double R[3][3];
    for (int i = 0; i < 3; ++i)
        for (int j = 0; j < 3; ++j)
            R[i][j] = Vs[i][0] * U[j][0] + Vs[i][1] * U[j][1] + Vs[i][2] * U[j][2];
    const double det =
        R[0][0] * (R[1][1] * R[2][2] - R[1][2] * R[2][1]) -
        R[0][1] * (R[1][0] * R[2][2] - R[1][2] * R[2][0]) +
        R[0][2] * (R[1][0] * R[2][1] - R[1][1] * R[2][0]);
    if (det < 0.0) {
        Vs[0][2] = -Vs[0][2]; Vs[1][2] = -Vs[1][2]; Vs[2][2] = -Vs[2][2];
        for (int i = 0; i < 3; ++i)
            for (int j = 0; j < 3; ++j)
                R[i][j] = Vs[i][0] * U[j][0] + Vs[i][1] * U[j][1] + Vs[i][2] * U[j][2];
    }

    double tvec[3];
    for (int i = 0; i < 3; ++i)
        tvec[i] = -(R[i][0] * mx[0] + R[i][1] * mx[1] + R[i][2] * mx[2]) + my[i];

    const double ex = atan2(R[2][1], R[2][2]);
    const double syv = sqrt(R[0][0] * R[0][0] + R[1][0] * R[1][0]);
    const double ey = atan2(-R[2][0], syv);
    const double ez = atan2(R[1][0], R[0][0]);

    for (int i = 0; i < 3; ++i)
        for (int j = 0; j < 3; ++j)
            out[b * 9 + i * 3 + j] = (float)R[i][j];
    out[72 + b * 3 + 0] = (float)tvec[0];
    out[72 + b * 3 + 1] = (float)tvec[1];
    out[72 + b * 3 + 2] = (float)tvec[2];
    out[96 + b * 3 + 0] = (float)ex;
    out[96 + b * 3 + 1] = (float)ey;
    out[96 + b * 3 + 2] = (float)ez;
}

// ------------------------------------------------------------------
extern "C" void kernel_launch(void* const* d_in, const int* in_sizes, int n_in,
                              void* d_out, int out_size, void* d_ws, size_t ws_size,
                              hipStream_t stream) {
    const float* qe  = (const float*)d_in[0];  // src_embedding [B,128,N]
    const float* te  = (const float*)d_in[1];  // tgt_embedding [B,128,N]
    const float* src = (const float*)d_in[2];  // src [B,3,N]
    const float* tgt = (const float*)d_in[3];  // tgt [B,3,N]
    float* out = (float*)d_out;

    ushort* qT   = (ushort*)d_ws;                    // bf16 [b][n][d] 6.3MB
    ushort* eT   = qT + QT_ELEMS;                    // bf16 [b][m][d] 6.3MB
    float4* part = (float4*)(eT + QT_ELEMS);         // MSPLIT*BN*NP float4

    k_prep<<<768, 256, 0, stream>>>(qe, te, qT, eT);
    k_attn<<<1536, 256, 0, stream>>>(qT, eT, tgt, part);
    k_final<<<BN, 256, 0, stream>>>(src, part, out);
}

// Round 7
// 70.075 us; speedup vs baseline: 4.6251x; 1.4931x over previous
//
#include <hip/hip_runtime.h>
#include <hip/hip_bf16.h>
#include <math.h>

#define BN 8
#define DEMB 128
#define NP 3072
#define MSPLIT 8
#define MRANGE (NP / MSPLIT)   // 384 m per block
#define NBLK 128               // n per block
#define NWAVE 32               // n per wave

#define QT_ELEMS ((size_t)BN * NP * DEMB)

typedef __attribute__((ext_vector_type(8))) short short8;
typedef __attribute__((ext_vector_type(4))) float f32x4;

__device__ inline float fast_exp2(float x) {
#if __has_builtin(__builtin_amdgcn_exp2f)
    return __builtin_amdgcn_exp2f(x);
#else
    return __expf(x * 0.6931471805599453f);
#endif
}

// ------------------------------------------------------------------
// k_prep: fp32 [b][d][n] -> bf16 [b][n][d], LDS-staged coalesced writes
// ------------------------------------------------------------------
#define PSTRIDE 132

__global__ __launch_bounds__(256) void k_prep(const float* __restrict__ qe,
                                              const float* __restrict__ te,
                                              ushort* __restrict__ qT,
                                              ushort* __restrict__ eT)
{
    __shared__ ushort lds[4][16 * PSTRIDE];

    const int bid = blockIdx.x;            // 2 * 8 * 48 = 768
    const int t   = bid & 1;
    const int b   = (bid >> 1) & 7;
    const int nb  = bid >> 4;              // 0..47

    const float* src = (t ? te : qe) + (size_t)b * DEMB * NP;
    ushort*      dst = (t ? eT : qT) + (size_t)b * NP * DEMB;

    const int w    = threadIdx.x >> 6;
    const int lane = threadIdx.x & 63;
    const int n0   = nb * 64 + w * 16;

#pragma unroll
    for (int p = 0; p < 8; ++p) {
        const int d  = p * 16 + (lane >> 2);
        const int nn = (lane & 3) * 4;
        const f32x4 v = *(const f32x4*)(src + (size_t)d * NP + n0 + nn);
#pragma unroll
        for (int k = 0; k < 4; ++k) {
            __hip_bfloat16 h = __float2bfloat16(v[k]);
            lds[w][(nn + k) * PSTRIDE + d] = *reinterpret_cast<ushort*>(&h);
        }
    }
    __syncthreads();

#pragma unroll
    for (int q = 0; q < 8; ++q) {
        const int flat = q * 256 + lane * 4;
        const int n = flat >> 7;
        const int d = flat & 127;
        uint2 vv;
        vv.x = *(const uint*)&lds[w][n * PSTRIDE + d];
        vv.y = *(const uint*)&lds[w][n * PSTRIDE + d + 2];
        *(uint2*)(dst + ((size_t)(n0 + n)) * DEMB + d) = vv;
    }
}

// ------------------------------------------------------------------
// k_attn: e-chunk (64m x 128d, 16KB) staged in LDS ONCE per block per
// chunk (reg -> ds_write_b128, XOR chunk-swizzle c^(row&7) on both write
// and read sides -> 2-way bank aliasing only, free). All 4 waves then
// fragment-read from LDS: 4x less L1/L2 read traffic than private
// re-reads. MFMA scores (S^T: rows=m, cols=n) + raw-exp softmax accum.
// ------------------------------------------------------------------
__global__ __launch_bounds__(256) void k_attn(const ushort* __restrict__ qT,
                                              const ushort* __restrict__ eT,
                                              const float* __restrict__ tgt,
                                              float4* __restrict__ part)
{
    __shared__ ushort esm[64][128];        // 16 KB swizzled e-chunk
    __shared__ float  tbuf[3][MRANGE];     // 4.6 KB tgt slice

    const int bid  = blockIdx.x;           // 1536 = 8b * 24nblk * 8ms
    const int b    = bid & 7;              // batch -> XCD pinning
    const int r    = bid >> 3;
    const int nblk = r % 24;
    const int ms   = r / 24;

    const int wid  = threadIdx.x >> 6;
    const int lane = threadIdx.x & 63;
    const int g    = lane >> 4;
    const int c16  = lane & 15;

    const int nw = nblk * NBLK + wid * NWAVE;
    const ushort* qb = qT + (size_t)b * NP * DEMB;
    const ushort* eb = eT + (size_t)b * NP * DEMB;
    const float*  tp = tgt + (size_t)b * 3 * NP;
    const int m_base = ms * MRANGE;

    // stage tgt slice into LDS (one time)
    for (int j = threadIdx.x; j < 3 * MRANGE; j += 256) {
        const int c = j / MRANGE, jm = j % MRANGE;
        tbuf[c][jm] = tp[c * NP + m_base + jm];
    }

    // B-frags (q), resident for the whole m-loop
    short8 bq[2][4];
#pragma unroll
    for (int ns = 0; ns < 2; ++ns)
#pragma unroll
        for (int kf = 0; kf < 4; ++kf)
            bq[ns][kf] = *(const short8*)(qb + (size_t)(nw + ns * 16 + c16) * DEMB
                                          + kf * 32 + g * 8);

    float o[2][4];   // o0,o1,o2,l
#pragma unroll
    for (int ns = 0; ns < 2; ++ns)
        o[ns][0] = o[ns][1] = o[ns][2] = o[ns][3] = 0.f;

    const float scale2 = 0.12752962736873462f;  // log2(e)/sqrt(128)

    // wave wid stages rows [wid*16, wid*16+16) of each 64-row chunk
    const int row_l = wid * 16 + c16;
    const int rxw   = row_l & 7;

    for (int mc = 0; mc < MRANGE / 64; ++mc) {
        const int m0 = m_base + mc * 64;

        // load my 16 rows (same access pattern as before, but only once/block)
        const ushort* ar = eb + (size_t)(m0 + row_l) * DEMB + g * 8;
        const short8 a0 = *(const short8*)(ar);
        const short8 a1 = *(const short8*)(ar + 32);
        const short8 a2 = *(const short8*)(ar + 64);
        const short8 a3 = *(const short8*)(ar + 96);

        __syncthreads();   // previous chunk fully consumed by all waves
        *(short8*)&esm[row_l][((g + 0) ^ rxw) * 8]  = a0;
        *(short8*)&esm[row_l][((g + 4) ^ rxw) * 8]  = a1;
        *(short8*)&esm[row_l][((g + 8) ^ rxw) * 8]  = a2;
        *(short8*)&esm[row_l][((g + 12) ^ rxw) * 8] = a3;
        __syncthreads();   // chunk visible to all waves

#pragma unroll
        for (int msub = 0; msub < 4; ++msub) {
            const int row = msub * 16 + c16;
            const int rx  = c16 & 7;        // row & 7
            const short8 e0 = *(const short8*)&esm[row][((g + 0) ^ rx) * 8];
            const short8 e1 = *(const short8*)&esm[row][((g + 4) ^ rx) * 8];
            const short8 e2 = *(const short8*)&esm[row][((g + 8) ^ rx) * 8];
            const short8 e3 = *(const short8*)&esm[row][((g + 12) ^ rx) * 8];

            f32x4 c0 = {0.f, 0.f, 0.f, 0.f};
            f32x4 c1 = {0.f, 0.f, 0.f, 0.f};
            c0 = __builtin_amdgcn_mfma_f32_16x16x32_bf16(e0, bq[0][0], c0, 0, 0, 0);
            c0 = __builtin_amdgcn_mfma_f32_16x16x32_bf16(e1, bq[0][1], c0, 0, 0, 0);
            c0 = __builtin_amdgcn_mfma_f32_16x16x32_bf16(e2, bq[0][2], c0, 0, 0, 0);
            c0 = __builtin_amdgcn_mfma_f32_16x16x32_bf16(e3, bq[0][3], c0, 0, 0, 0);
            c1 = __builtin_amdgcn_mfma_f32_16x16x32_bf16(e0, bq[1][0], c1, 0, 0, 0);
            c1 = __builtin_amdgcn_mfma_f32_16x16x32_bf16(e1, bq[1][1], c1, 0, 0, 0);
            c1 = __builtin_amdgcn_mfma_f32_16x16x32_bf16(e2, bq[1][2], c1, 0, 0, 0);
            c1 = __builtin_amdgcn_mfma_f32_16x16x32_bf16(e3, bq[1][3], c1, 0, 0, 0);

            const int mloc = mc * 64 + msub * 16;
            const f32x4 t0 = *(const f32x4*)&tbuf[0][mloc + g * 4];
            const f32x4 t1 = *(const f32x4*)&tbuf[1][mloc + g * 4];
            const f32x4 t2 = *(const f32x4*)&tbuf[2][mloc + g * 4];

#pragma unroll
            for (int rr = 0; rr < 4; ++rr) {
                const float p0 = fast_exp2(c0[rr] * scale2);
                o[0][3] += p0;
                o[0][0] = fmaf(p0, t0[rr], o[0][0]);
                o[0][1] = fmaf(p0, t1[rr], o[0][1]);
                o[0][2] = fmaf(p0, t2[rr], o[0][2]);
                const float p1 = fast_exp2(c1[rr] * scale2);
                o[1][3] += p1;
                o[1][0] = fmaf(p1, t0[rr], o[1][0]);
                o[1][1] = fmaf(p1, t1[rr], o[1][1]);
                o[1][2] = fmaf(p1, t2[rr], o[1][2]);
            }
        }
    }

    // reduce over the 4 m-row lane groups, write float4 partial
#pragma unroll
    for (int ns = 0; ns < 2; ++ns) {
#pragma unroll
        for (int v = 0; v < 4; ++v) {
            o[ns][v] += __shfl_xor(o[ns][v], 16);
            o[ns][v] += __shfl_xor(o[ns][v], 32);
        }
        if (g == 0) {
            const int n = nw + ns * 16 + c16;
            float4 pv;
            pv.x = o[ns][0]; pv.y = o[ns][1]; pv.z = o[ns][2]; pv.w = o[ns][3];
            part[((size_t)ms * BN + b) * NP + n] = pv;
        }
    }
}

// ------------------------------------------------------------------
// k_final: fused combine + per-batch reduction + 3x3 SVD + R, t, euler
// ------------------------------------------------------------------
__global__ __launch_bounds__(256) void k_final(const float* __restrict__ src,
                                               const float4* __restrict__ part,
                                               float* __restrict__ out)
{
    const int b = blockIdx.x;
    const float* sp = src + (size_t)b * 3 * NP;

    double acc[15];
#pragma unroll
    for (int v = 0; v < 15; ++v) acc[v] = 0.0;

    for (int n = threadIdx.x; n < NP; n += 256) {
        float o0 = 0.f, o1 = 0.f, o2 = 0.f, l = 0.f;
#pragma unroll
        for (int s = 0; s < MSPLIT; ++s) {
            const float4 pp = part[((size_t)s * BN + b) * NP + n];
            o0 += pp.x; o1 += pp.y; o2 += pp.z; l += pp.w;
        }
        const double inv = 1.0 / (double)l;
        const double y0 = o0 * inv, y1 = o1 * inv, y2 = o2 * inv;
        const double x0 = sp[n], x1 = sp[NP + n], x2 = sp[2 * NP + n];
        acc[0] += x0; acc[1] += x1; acc[2] += x2;
        acc[3] += y0; acc[4] += y1; acc[5] += y2;
        acc[6]  += x0 * y0; acc[7]  += x0 * y1; acc[8]  += x0 * y2;
        acc[9]  += x1 * y0; acc[10] += x1 * y1; acc[11] += x1 * y2;
        acc[12] += x2 * y0; acc[13] += x2 * y1; acc[14] += x2 * y2;
    }

    const int wid = threadIdx.x >> 6, lane = threadIdx.x & 63;
#pragma unroll
    for (int v = 0; v < 15; ++v)
#pragma unroll
        for (int mask = 32; mask >= 1; mask >>= 1)
            acc[v] += __shfl_xor(acc[v], mask);

    __shared__ double red[4][15];
    if (lane == 0) {
#pragma unroll
        for (int v = 0; v < 15; ++v) red[wid][v] = acc[v];
    }
    __syncthreads();
    if (threadIdx.x != 0) return;

    double t15[15];
#pragma unroll
    for (int v = 0; v < 15; ++v)
        t15[v] = red[0][v] + red[1][v] + red[2][v] + red[3][v];

    const double invN = 1.0 / NP;
    const double mx[3] = {t15[0] * invN, t15[1] * invN, t15[2] * invN};
    const double my[3] = {t15[3] * invN, t15[4] * invN, t15[5] * invN};
    double H[3][3];
#pragma unroll
    for (int i = 0; i < 3; ++i)
#pragma unroll
        for (int j = 0; j < 3; ++j)
            H[i][j] = t15[6 + i * 3 + j] - (double)NP * mx[i] * my[j];

    double A[3][3], V[3][3];
#pragma unroll
    for (int i = 0; i < 3; ++i)
#pragma unroll
        for (int j = 0; j < 3; ++j) {
            A[i][j] = H[0][i] * H[0][j] + H[1][i] * H[1][j] + H[2][i] * H[2][j];
            V[i][j] = (i == j) ? 1.0 : 0.0;
        }

    for (int sweep = 0; sweep < 12; ++sweep) {
        const int pqs[3][2] = {{0, 1}, {0, 2}, {1, 2}};
        for (int k = 0; k < 3; ++k) {
            const int p = pqs[k][0], q = pqs[k][1];
            const double apq = A[p][q];
            if (apq * apq <= 1e-24 * (A[p][p] * A[p][p] + A[q][q] * A[q][q]))
                continue;
            const double theta = (A[q][q] - A[p][p]) / (2.0 * apq);
            const double tj = (theta >= 0 ? 1.0 : -1.0) /
                              (fabs(theta) + sqrt(theta * theta + 1.0));
            const double c = 1.0 / sqrt(tj * tj + 1.0);
            const double s = tj * c;
            for (int i = 0; i < 3; ++i) {
                const double aip = A[i][p], aiq = A[i][q];
                A[i][p] = c * aip - s * aiq;
                A[i][q] = s * aip + c * aiq;
            }
            for (int i = 0; i < 3; ++i) {
                const double api = A[p][i], aqi = A[q][i];
                A[p][i] = c * api - s * aqi;
                A[q][i] = s * api + c * aqi;
            }
            for (int i = 0; i < 3; ++i) {
                const double vip = V[i][p], viq = V[i][q];
                V[i][p] = c * vip - s * viq;
                V[i][q] = s * vip + c * viq;
            }
        }
    }

    double lam[3] = {A[0][0], A[1][1], A[2][2]};
    int ord[3] = {0, 1, 2};
    for (int i = 0; i < 2; ++i)
        for (int j = i + 1; j < 3; ++j)
            if (lam[ord[j]] > lam[ord[i]]) { int t = ord[i]; ord[i] = ord[j]; ord[j] = t; }

    double Vs[3][3], sv[3];
    for (int j = 0; j < 3; ++j) {
        sv[j] = sqrt(fmax(lam[ord[j]], 0.0));
        for (int i = 0; i < 3; ++i) Vs[i][j] = V[i][ord[j]];
    }
    double U[3][3];
    for (int j = 0; j < 3; ++j) {
        const double h0 = H[0][0] * Vs[0][j] + H[0][1] * Vs[1][j] + H[0][2] * Vs[2][j];
        const double h1 = H[1][0] * Vs[0][j] + H[1][1] * Vs[1][j] + H[1][2] * Vs[2][j];
        const double h2 = H[2][0] * Vs[0][j] + H[2][1] * Vs[1][j] + H[2][2] * Vs[2][j];
        const double inv = 1.0 / fmax(sv[j], 1e-300);
        U[0][j] = h0 * inv; U[1][j] = h1 * inv; U[2][j] = h2 * inv;
    }

    double R[3][3];
    for (int i = 0; i < 3; ++i)
        for (int j = 0; j < 3; ++j)
            R[i][j] = Vs[i][0] * U[j][0] + Vs[i][1] * U[j][1] + Vs[i][2] * U[j][2];
    const double det =
        R[0][0] * (R[1][1] * R[2][2] - R[1][2] * R[2][1]) -
        R[0][1] * (R[1][0] * R[2][2] - R[1][2] * R[2][0]) +
        R[0][2] * (R[1][0] * R[2][1] - R[1][1] * R[2][0]);
    if (det < 0.0) {
        Vs[0][2] = -Vs[0][2]; Vs[1][2] = -Vs[1][2]; Vs[2][2] = -Vs[2][2];
        for (int i = 0; i < 3; ++i)
            for (int j = 0; j < 3; ++j)
                R[i][j] = Vs[i][0] * U[j][0] + Vs[i][1] * U[j][1] + Vs[i][2] * U[j][2];
    }

    double tvec[3];
    for (int i = 0; i < 3; ++i)
        tvec[i] = -(R[i][0] * mx[0] + R[i][1] * mx[1] + R[i][2] * mx[2]) + my[i];

    const double ex = atan2(R[2][1], R[2][2]);
    const double syv = sqrt(R[0][0] * R[0][0] + R[1][0] * R[1][0]);
    const double ey = atan2(-R[2][0], syv);
    const double ez = atan2(R[1][0], R[0][0]);

    for (int i = 0; i < 3; ++i)
        for (int j = 0; j < 3; ++j)
            out[b * 9 + i * 3 + j] = (float)R[i][j];
    out[72 + b * 3 + 0] = (float)tvec[0];
    out[72 + b * 3 + 1] = (float)tvec[1];
    out[72 + b * 3 + 2] = (float)tvec[2];
    out[96 + b * 3 + 0] = (float)ex;
    out[96 + b * 3 + 1] = (float)ey;
    out[96 + b * 3 + 2] = (float)ez;
}

// ------------------------------------------------------------------
extern "C" void kernel_launch(void* const* d_in, const int* in_sizes, int n_in,
                              void* d_out, int out_size, void* d_ws, size_t ws_size,
                              hipStream_t stream) {
    const float* qe  = (const float*)d_in[0];  // src_embedding [B,128,N]
    const float* te  = (const float*)d_in[1];  // tgt_embedding [B,128,N]
    const float* src = (const float*)d_in[2];  // src [B,3,N]
    const float* tgt = (const float*)d_in[3];  // tgt [B,3,N]
    float* out = (float*)d_out;

    ushort* qT   = (ushort*)d_ws;                    // bf16 [b][n][d] 6.3MB
    ushort* eT   = qT + QT_ELEMS;                    // bf16 [b][m][d] 6.3MB
    float4* part = (float4*)(eT + QT_ELEMS);         // MSPLIT*BN*NP float4

    k_prep<<<768, 256, 0, stream>>>(qe, te, qT, eT);
    k_attn<<<1536, 256, 0, stream>>>(qT, eT, tgt, part);
    k_final<<<BN, 256, 0, stream>>>(src, part, out);
}